// Round 1
// baseline (2262.161 us; speedup 1.0000x reference)
//
#include <hip/hip_runtime.h>
#include <hip/hip_bf16.h>

static constexpr int B_ = 8;

// ---------- prep: transpose conv weights [OC][ICKK] -> [ICKK][OC] ----------
__global__ void k_transpose_w(const float* __restrict__ src, float* __restrict__ dst,
                              int oc_n, int ickk_n) {
  int idx = blockIdx.x * 256 + threadIdx.x;
  int n = oc_n * ickk_n;
  if (idx >= n) return;
  int oc = idx / ickk_n, ickk = idx - oc * ickk_n;
  dst[ickk * oc_n + oc] = src[idx];
}

// ---------- cond conv1: 7x7 s2 p1, 64->32, relu. out [8,32,126,126] ----------
__global__ __launch_bounds__(256) void k_cond1(const float* __restrict__ x,
    const float* __restrict__ wt /*[3136][32]*/, const float* __restrict__ cb,
    float* __restrict__ h1) {
  const int b = blockIdx.z;
  const int ty0 = blockIdx.y * 16, tx0 = blockIdx.x * 16;
  const int tid = threadIdx.x, tx = tid & 15, ty = tid >> 4;
  __shared__ float lx[8 * 1369];  // 8 ch x 37x37
  float acc[32];
#pragma unroll
  for (int o = 0; o < 32; ++o) acc[o] = 0.f;
  const int ih0 = 2 * ty0 - 1, iw0 = 2 * tx0 - 1;
  for (int c0 = 0; c0 < 64; c0 += 8) {
    __syncthreads();
    for (int idx = tid; idx < 8 * 1369; idx += 256) {
      int ch = idx / 1369, r = idx - ch * 1369;
      int ih = ih0 + r / 37, iw = iw0 + r % 37;
      float v = 0.f;
      if ((unsigned)ih < 256u && (unsigned)iw < 256u)
        v = x[(((b * 64) + c0 + ch) * 256 + ih) * 256 + iw];
      lx[idx] = v;
    }
    __syncthreads();
#pragma unroll 1
    for (int ch = 0; ch < 8; ++ch) {
      const float* wrow = wt + (c0 + ch) * 49 * 32;
#pragma unroll 1
      for (int kh = 0; kh < 7; ++kh) {
        const float* lrow = lx + ch * 1369 + (2 * ty + kh) * 37 + 2 * tx;
#pragma unroll
        for (int kw = 0; kw < 7; ++kw) {
          float xv = lrow[kw];
          const float* wk = wrow + (kh * 7 + kw) * 32;
#pragma unroll
          for (int o = 0; o < 32; ++o) acc[o] = fmaf(wk[o], xv, acc[o]);
        }
      }
    }
  }
  int oh = ty0 + ty, ow = tx0 + tx;
  if (oh < 126 && ow < 126) {
#pragma unroll
    for (int o = 0; o < 32; ++o)
      h1[((b * 32 + o) * 126 + oh) * 126 + ow] = fmaxf(acc[o] + cb[o], 0.f);
  }
}

// ---------- cond conv2/3: 3x3 s2 p1, 32->32, relu ----------
template <int HI, int HO>
__global__ __launch_bounds__(256) void k_cond23(const float* __restrict__ in,
    const float* __restrict__ wt /*[288][32]*/, const float* __restrict__ cb,
    float* __restrict__ out) {
  const int b = blockIdx.z;
  const int ty0 = blockIdx.y * 16, tx0 = blockIdx.x * 16;
  const int tid = threadIdx.x, tx = tid & 15, ty = tid >> 4;
  __shared__ float lx[8 * 1089];  // 8 ch x 33x33
  float acc[32];
#pragma unroll
  for (int o = 0; o < 32; ++o) acc[o] = 0.f;
  const int ih0 = 2 * ty0 - 1, iw0 = 2 * tx0 - 1;
  for (int c0 = 0; c0 < 32; c0 += 8) {
    __syncthreads();
    for (int idx = tid; idx < 8 * 1089; idx += 256) {
      int ch = idx / 1089, r = idx - ch * 1089;
      int ih = ih0 + r / 33, iw = iw0 + r % 33;
      float v = 0.f;
      if ((unsigned)ih < (unsigned)HI && (unsigned)iw < (unsigned)HI)
        v = in[((b * 32 + c0 + ch) * HI + ih) * HI + iw];
      lx[idx] = v;
    }
    __syncthreads();
#pragma unroll 1
    for (int ch = 0; ch < 8; ++ch) {
      const float* wrow = wt + (c0 + ch) * 9 * 32;
#pragma unroll
      for (int kh = 0; kh < 3; ++kh) {
        const float* lrow = lx + ch * 1089 + (2 * ty + kh) * 33 + 2 * tx;
#pragma unroll
        for (int kw = 0; kw < 3; ++kw) {
          float xv = lrow[kw];
          const float* wk = wrow + (kh * 3 + kw) * 32;
#pragma unroll
          for (int o = 0; o < 32; ++o) acc[o] = fmaf(wk[o], xv, acc[o]);
        }
      }
    }
  }
  int oh = ty0 + ty, ow = tx0 + tx;
  if (oh < HO && ow < HO) {
#pragma unroll
    for (int o = 0; o < 32; ++o)
      out[((b * 32 + o) * HO + oh) * HO + ow] = fmaxf(acc[o] + cb[o], 0.f);
  }
}

// ---------- mean over 32x32 -> cond[8*32] ----------
__global__ void k_mean(const float* __restrict__ h3, float* __restrict__ cond) {
  int bo = blockIdx.x;  // 0..255
  int tid = threadIdx.x;
  float s = 0.f;
  for (int i = tid; i < 1024; i += 256) s += h3[bo * 1024 + i];
  __shared__ float red[256];
  red[tid] = s;
  __syncthreads();
  for (int o = 128; o > 0; o >>= 1) {
    if (tid < o) red[tid] += red[tid + o];
    __syncthreads();
  }
  if (tid == 0) cond[bo] = red[0] * (1.f / 1024.f);
}

// ---------- FiLM: a = scale+1, bias1 = a*b0 + shift, bias2 ----------
__global__ void k_film(const float* __restrict__ cond,
                       const float* __restrict__ scale_w, const float* __restrict__ scale_b,
                       const float* __restrict__ shift_w, const float* __restrict__ shift_b,
                       const float* __restrict__ share1_b, const float* __restrict__ share2_b,
                       float* __restrict__ a_, float* __restrict__ bias1,
                       float* __restrict__ bias2) {
  int t = threadIdx.x;  // 512
  int b = t >> 6, j = t & 63;
  float s = scale_b[j], sh = shift_b[j];
  for (int k = 0; k < 32; ++k) {
    float c = cond[b * 32 + k];
    s = fmaf(c, scale_w[j * 32 + k], s);
    sh = fmaf(c, shift_w[j * 32 + k], sh);
  }
  float a = s + 1.f;
  float b0 = (j < 32) ? 0.f : share1_b[j - 32];
  a_[t] = a;
  bias1[t] = fmaf(a, b0, sh);
  bias2[t] = (j < 32) ? 0.f : share2_b[j - 32];
}

// ---------- merge dyn*ow | share into [b][576][64] (optionally *a) ----------
__global__ void k_prep(const float* __restrict__ dyn, const float* __restrict__ ow,
                       const float* __restrict__ share, const float* __restrict__ a_,
                       float* __restrict__ w_all, int use_a) {
  int idx = blockIdx.x * 256 + threadIdx.x;  // n = 8*576*64
  if (idx >= B_ * 576 * 64) return;
  int b = idx / (576 * 64), r = idx - b * 576 * 64;
  int ickk = r >> 6, oc = r & 63;
  float v = (oc < 32) ? dyn[oc * 576 + ickk] * ow[(b * 32 + oc) * 576 + ickk]
                      : share[(oc - 32) * 576 + ickk];
  if (use_a) v *= a_[b * 64 + oc];
  w_all[idx] = v;
}

// ---------- HDA conv: 3x3 s1 p1, 64->64 ----------
// STAGE 1: out = relu(conv + bias)       (FiLM folded into w/bias)
// STAGE 2: out = resid + conv + bias
template <int STAGE>
__global__ __launch_bounds__(256) void k_hda(const float* __restrict__ in,
    const float* __restrict__ w /*[b][576][64]*/, const float* __restrict__ bias /*[b][64]*/,
    const float* __restrict__ resid, float* __restrict__ out) {
  const int b = blockIdx.z;
  const int ty0 = blockIdx.y * 16, tx0 = blockIdx.x * 16;
  const int tid = threadIdx.x, tx = tid & 15, ty = tid >> 4;
  __shared__ float lx[16 * 324];  // 16 ch x 18x18
  float acc[64];
#pragma unroll
  for (int o = 0; o < 64; ++o) acc[o] = 0.f;
  const float* wb = w + b * 576 * 64;
  for (int c0 = 0; c0 < 64; c0 += 16) {
    __syncthreads();
    for (int idx = tid; idx < 16 * 324; idx += 256) {
      int ch = idx / 324, r = idx - ch * 324;
      int ih = ty0 - 1 + r / 18, iw = tx0 - 1 + r % 18;
      float v = 0.f;
      if ((unsigned)ih < 256u && (unsigned)iw < 256u)
        v = in[((b * 64 + c0 + ch) * 256 + ih) * 256 + iw];
      lx[idx] = v;
    }
    __syncthreads();
#pragma unroll 1
    for (int ch = 0; ch < 16; ++ch) {
      const float* wrow = wb + (c0 + ch) * 9 * 64;
      const float* lbase = lx + ch * 324 + ty * 18 + tx;
#pragma unroll
      for (int k = 0; k < 9; ++k) {
        float xv = lbase[(k / 3) * 18 + (k % 3)];
        const float* wk = wrow + k * 64;
#pragma unroll
        for (int o = 0; o < 64; ++o) acc[o] = fmaf(wk[o], xv, acc[o]);
      }
    }
  }
  const int oh = ty0 + ty, ow2 = tx0 + tx;
  const float* bb = bias + b * 64;
  size_t base = ((size_t)b * 64 * 65536) + (size_t)oh * 256 + ow2;
#pragma unroll
  for (int o = 0; o < 64; ++o) {
    float v = acc[o] + bb[o];
    if (STAGE == 1) {
      v = fmaxf(v, 0.f);
    } else {
      v += resid[base + (size_t)o * 65536];
    }
    out[base + (size_t)o * 65536] = v;
  }
}

extern "C" void kernel_launch(void* const* d_in, const int* in_sizes, int n_in,
                              void* d_out, int out_size, void* d_ws, size_t ws_size,
                              hipStream_t stream) {
  const float* x        = (const float*)d_in[0];
  const float* ow1      = (const float*)d_in[1];
  const float* ow2      = (const float*)d_in[2];
  const float* cw1      = (const float*)d_in[3];
  const float* cb1      = (const float*)d_in[4];
  const float* cw2      = (const float*)d_in[5];
  const float* cb2      = (const float*)d_in[6];
  const float* cw3      = (const float*)d_in[7];
  const float* cb3      = (const float*)d_in[8];
  const float* scale_w  = (const float*)d_in[9];
  const float* scale_b  = (const float*)d_in[10];
  const float* shift_w  = (const float*)d_in[11];
  const float* shift_b  = (const float*)d_in[12];
  const float* dyn1     = (const float*)d_in[13];
  const float* share1   = (const float*)d_in[14];
  const float* share1_b = (const float*)d_in[15];
  const float* dyn2     = (const float*)d_in[16];
  const float* share2   = (const float*)d_in[17];
  const float* share2_b = (const float*)d_in[18];
  float* out = (float*)d_out;
  float* ws = (float*)d_ws;

  // persistent region (must survive into the HDA convs)
  float* w1    = ws;                       // 8*576*64
  float* w2    = w1 + (size_t)8 * 576 * 64;
  float* a_    = w2 + (size_t)8 * 576 * 64;  // 512
  float* bias1 = a_ + 512;                   // 512
  float* bias2 = bias1 + 512;                // 512
  float* cond  = bias2 + 512;                // 256
  float* mid   = cond + 256;                 // 8*64*256*256
  // temporaries overlapping mid (all dead before k_hda<1> writes mid)
  float* h1   = mid;                                  // 8*32*126*126
  float* h2   = h1 + (size_t)8 * 32 * 126 * 126;      // 8*32*63*63
  float* h3   = h2 + (size_t)8 * 32 * 63 * 63;        // 8*32*32*32
  float* cw1t = h3 + (size_t)8 * 32 * 32 * 32;        // 3136*32
  float* cw2t = cw1t + 3136 * 32;                     // 288*32
  float* cw3t = cw2t + 288 * 32;                      // 288*32

  k_transpose_w<<<(32 * 3136 + 255) / 256, 256, 0, stream>>>(cw1, cw1t, 32, 3136);
  k_transpose_w<<<(32 * 288 + 255) / 256, 256, 0, stream>>>(cw2, cw2t, 32, 288);
  k_transpose_w<<<(32 * 288 + 255) / 256, 256, 0, stream>>>(cw3, cw3t, 32, 288);

  k_cond1<<<dim3(8, 8, 8), 256, 0, stream>>>(x, cw1t, cb1, h1);
  k_cond23<126, 63><<<dim3(4, 4, 8), 256, 0, stream>>>(h1, cw2t, cb2, h2);
  k_cond23<63, 32><<<dim3(2, 2, 8), 256, 0, stream>>>(h2, cw3t, cb3, h3);
  k_mean<<<256, 256, 0, stream>>>(h3, cond);
  k_film<<<1, 512, 0, stream>>>(cond, scale_w, scale_b, shift_w, shift_b,
                                share1_b, share2_b, a_, bias1, bias2);

  k_prep<<<(8 * 576 * 64 + 255) / 256, 256, 0, stream>>>(dyn1, ow1, share1, a_, w1, 1);
  k_prep<<<(8 * 576 * 64 + 255) / 256, 256, 0, stream>>>(dyn2, ow2, share2, a_, w2, 0);

  k_hda<1><<<dim3(16, 16, 8), 256, 0, stream>>>(x, w1, bias1, nullptr, mid);
  k_hda<2><<<dim3(16, 16, 8), 256, 0, stream>>>(mid, w2, bias2, x, out);
}

// Round 2
// 497.940 us; speedup vs baseline: 4.5430x; 4.5430x over previous
//
#include <hip/hip_runtime.h>

typedef unsigned short u16;
typedef unsigned int u32;
typedef __attribute__((ext_vector_type(8))) __bf16 bf16x8;
typedef __attribute__((ext_vector_type(8))) u16 u16x8;
typedef __attribute__((ext_vector_type(4))) float f32x4;

__device__ __forceinline__ u16 f2bf(float f) {
  u32 u = __builtin_bit_cast(u32, f);
  u = (u + 0x7FFFu + ((u >> 16) & 1u)) >> 16;
  return (u16)u;
}

__device__ __forceinline__ f32x4 mfma16(bf16x8 a, bf16x8 b, f32x4 c) {
  return __builtin_amdgcn_mfma_f32_16x16x32_bf16(a, b, c, 0, 0, 0);
}

// ---------- NCHW f32 -> NHWC bf16 transpose of x ----------
__global__ __launch_bounds__(256) void k_tr(const float* __restrict__ x,
                                            u16* __restrict__ xh) {
  __shared__ float t[64][33];
  const int b = blockIdx.z, y = blockIdx.y, x0 = blockIdx.x * 32;
  const int tid = threadIdx.x;
  {
    int ic = tid >> 2, xo = (tid & 3) * 8;
    const float* s = x + (((size_t)b * 64 + ic) * 256 + y) * 256 + x0 + xo;
    f32x4 v0 = *(const f32x4*)s;
    f32x4 v1 = *(const f32x4*)(s + 4);
#pragma unroll
    for (int j = 0; j < 4; ++j) { t[ic][xo + j] = v0[j]; t[ic][xo + 4 + j] = v1[j]; }
  }
  __syncthreads();
  {
    int xc = tid >> 3, ic0 = (tid & 7) * 8;
    u16x8 v;
#pragma unroll
    for (int j = 0; j < 8; ++j) v[j] = f2bf(t[ic0 + j][xc]);
    *(u16x8*)(xh + (((size_t)b * 256 + y) * 256 + x0 + xc) * 64 + ic0) = v;
  }
}

// ---------- cond conv weights: [OC][IC][K][K] f32 -> [oc][tap*IC+ic] bf16 ----------
__global__ void k_prep_cw(const float* __restrict__ src, u16* __restrict__ dst,
                          int IC, int KK2, int n) {
  int d = blockIdx.x * 256 + threadIdx.x;
  if (d >= n) return;
  int per = KK2 * IC;
  int oc = d / per, r = d - oc * per;
  int tap = r / IC, ic = r - tap * IC;
  dst[d] = f2bf(src[(oc * IC + ic) * KK2 + tap]);
}

// ---------- HDA weights: merge dyn*ow | share (optionally *a) -> [b][oc][576] bf16 ----------
__global__ void k_prep_hda(const float* __restrict__ dyn, const float* __restrict__ ow,
                           const float* __restrict__ share, const float* __restrict__ a_,
                           u16* __restrict__ dst, int use_a) {
  int d = blockIdx.x * 256 + threadIdx.x;
  if (d >= 8 * 64 * 576) return;
  int b = d / 36864, r = d - b * 36864;
  int oc = r / 576, k = r - oc * 576;
  int tap = k >> 6, ic = k & 63;
  float v = (oc < 32) ? dyn[(oc * 64 + ic) * 9 + tap] * ow[((b * 32 + oc) * 64 + ic) * 9 + tap]
                      : share[((oc - 32) * 64 + ic) * 9 + tap];
  if (use_a) v *= a_[b * 64 + oc];
  dst[d] = f2bf(v);
}

// ---------- generic stride-2 pad-1 conv, 32 oc, MFMA, A from global NHWC bf16 ----------
// OUTF32=0: dst NHWC bf16 [b][HO][HO][32];  OUTF32=1: dst NCHW f32 [b][32][HO][HO]
template <int HI, int HO, int IC, int KK, int OUTF32>
__global__ __launch_bounds__(256, 4) void k_conv_s2(const u16* __restrict__ src,
    const u16* __restrict__ wgt, const float* __restrict__ bias, void* __restrict__ dst) {
  const int b = blockIdx.z;
  const int by0 = blockIdx.y * 8, bx0 = blockIdx.x * 16;
  const int tid = threadIdx.x, lane = tid & 63, wid = tid >> 6;
  const int col = lane & 15, kq = lane >> 4;
  f32x4 acc[2][2];
#pragma unroll
  for (int i = 0; i < 2; ++i)
#pragma unroll
    for (int j = 0; j < 2; ++j) acc[i][j] = 0.f;
  const u16x8 Z = (u16x8)0;
#pragma unroll 1
  for (int kh = 0; kh < KK; ++kh) {
#pragma unroll
    for (int kw = 0; kw < KK; ++kw) {
#pragma unroll
      for (int h = 0; h < IC / 32; ++h) {
        bf16x8 a[2];
#pragma unroll
        for (int mf = 0; mf < 2; ++mf) {
          int oh = by0 + wid * 2 + mf;
          int ih = 2 * oh - 1 + kh;
          int ix = 2 * (bx0 + col) - 1 + kw;
          int ic = h * 32 + kq * 8;
          u16x8 raw = Z;
          if ((unsigned)ih < (unsigned)HI && (unsigned)ix < (unsigned)HI)
            raw = *(const u16x8*)(src + (((size_t)b * HI + ih) * HI + ix) * IC + ic);
          a[mf] = __builtin_bit_cast(bf16x8, raw);
        }
        int k0 = (kh * KK + kw) * IC + h * 32 + kq * 8;
        bf16x8 w[2];
#pragma unroll
        for (int nf = 0; nf < 2; ++nf)
          w[nf] = __builtin_bit_cast(bf16x8,
                    *(const u16x8*)(wgt + (size_t)(nf * 16 + col) * (KK * KK * IC) + k0));
#pragma unroll
        for (int mf = 0; mf < 2; ++mf)
#pragma unroll
          for (int nf = 0; nf < 2; ++nf) acc[mf][nf] = mfma16(a[mf], w[nf], acc[mf][nf]);
      }
    }
  }
#pragma unroll
  for (int mf = 0; mf < 2; ++mf) {
    int oh = by0 + wid * 2 + mf;
    if (oh >= HO) continue;
#pragma unroll
    for (int nf = 0; nf < 2; ++nf) {
      int oc = nf * 16 + col;
      float bv = bias[oc];
#pragma unroll
      for (int r = 0; r < 4; ++r) {
        int ow = bx0 + kq * 4 + r;
        if (ow >= HO) continue;
        float v = fmaxf(acc[mf][nf][r] + bv, 0.f);
        if (OUTF32)
          ((float*)dst)[(((size_t)b * 32 + oc) * HO + oh) * HO + ow] = v;
        else
          ((u16*)dst)[(((size_t)b * HO + oh) * HO + ow) * 32 + oc] = f2bf(v);
      }
    }
  }
}

// ---------- mean over 32x32 -> cond[8*32] ----------
__global__ void k_mean(const float* __restrict__ h3, float* __restrict__ cond) {
  int bo = blockIdx.x;
  int tid = threadIdx.x;
  float s = 0.f;
  for (int i = tid; i < 1024; i += 256) s += h3[bo * 1024 + i];
  __shared__ float red[256];
  red[tid] = s;
  __syncthreads();
  for (int o = 128; o > 0; o >>= 1) {
    if (tid < o) red[tid] += red[tid + o];
    __syncthreads();
  }
  if (tid == 0) cond[bo] = red[0] * (1.f / 1024.f);
}

// ---------- FiLM fold ----------
__global__ void k_film(const float* __restrict__ cond,
                       const float* __restrict__ scale_w, const float* __restrict__ scale_b,
                       const float* __restrict__ shift_w, const float* __restrict__ shift_b,
                       const float* __restrict__ share1_b, const float* __restrict__ share2_b,
                       float* __restrict__ a_, float* __restrict__ bias1,
                       float* __restrict__ bias2) {
  int t = threadIdx.x;  // 512
  int b = t >> 6, j = t & 63;
  float s = scale_b[j], sh = shift_b[j];
  for (int k = 0; k < 32; ++k) {
    float c = cond[b * 32 + k];
    s = fmaf(c, scale_w[j * 32 + k], s);
    sh = fmaf(c, shift_w[j * 32 + k], sh);
  }
  float a = s + 1.f;
  float b0 = (j < 32) ? 0.f : share1_b[j - 32];
  a_[t] = a;
  bias1[t] = fmaf(a, b0, sh);
  bias2[t] = (j < 32) ? 0.f : share2_b[j - 32];
}

// ---------- HDA conv 3x3 s1 p1 64->64, MFMA, LDS-staged 16x16 tile ----------
// STAGE 1: dst = NHWC bf16 relu(conv+bias);  STAGE 2: dst = NCHW f32 resid+conv+bias
template <int STAGE>
__global__ __launch_bounds__(256, 3) void k_hda_mfma(const u16* __restrict__ asrc,
    const u16* __restrict__ wall, const float* __restrict__ bias,
    const float* __restrict__ resid, void* __restrict__ dst) {
  __shared__ char lds[41472];  // 18*18 positions x 64 ic bf16, swizzled
  const int b = blockIdx.z;
  const int by0 = blockIdx.y * 16, bx0 = blockIdx.x * 16;
  const int tid = threadIdx.x;
  const u16x8 Z = (u16x8)0;
  for (int i = tid; i < 2592; i += 256) {
    int L = i >> 3, c = i & 7;
    int yy = L / 18, xx = L - yy * 18;
    int gy = by0 - 1 + yy, gx = bx0 - 1 + xx;
    u16x8 v = Z;
    if ((unsigned)gy < 256u && (unsigned)gx < 256u)
      v = *(const u16x8*)(asrc + (((size_t)b * 256 + gy) * 256 + gx) * 64 + c * 8);
    int off = (L * 128 + c * 16) ^ ((L & 7) << 4);
    *(u16x8*)(lds + off) = v;
  }
  __syncthreads();
  const int lane = tid & 63, wid = tid >> 6;
  const int col = lane & 15, kq = lane >> 4;
  f32x4 acc[4][4];
#pragma unroll
  for (int i = 0; i < 4; ++i)
#pragma unroll
    for (int j = 0; j < 4; ++j) acc[i][j] = 0.f;
  const u16* wb = wall + (size_t)b * 64 * 576;
#pragma unroll 1
  for (int tap = 0; tap < 9; ++tap) {
    const int kh = tap / 3, kw = tap - kh * 3;
#pragma unroll
    for (int h = 0; h < 2; ++h) {
      bf16x8 a[4];
#pragma unroll
      for (int mf = 0; mf < 4; ++mf) {
        int L = (wid * 4 + mf + kh) * 18 + (col + kw);
        int ic = h * 32 + kq * 8;
        int off = (L * 128 + ic * 2) ^ ((L & 7) << 4);
        a[mf] = __builtin_bit_cast(bf16x8, *(const u16x8*)(lds + off));
      }
      int k0 = tap * 64 + h * 32 + kq * 8;
      bf16x8 w[4];
#pragma unroll
      for (int nf = 0; nf < 4; ++nf)
        w[nf] = __builtin_bit_cast(bf16x8, *(const u16x8*)(wb + (size_t)(nf * 16 + col) * 576 + k0));
#pragma unroll
      for (int mf = 0; mf < 4; ++mf)
#pragma unroll
        for (int nf = 0; nf < 4; ++nf) acc[mf][nf] = mfma16(a[mf], w[nf], acc[mf][nf]);
    }
  }
  const float* bb = bias + b * 64;
#pragma unroll
  for (int mf = 0; mf < 4; ++mf) {
    int y = by0 + wid * 4 + mf;
#pragma unroll
    for (int nf = 0; nf < 4; ++nf) {
      int oc = nf * 16 + col;
      float bv = bb[oc];
      if (STAGE == 1) {
        size_t base = (((size_t)b * 256 + y) * 256 + (bx0 + kq * 4)) * 64 + oc;
#pragma unroll
        for (int r = 0; r < 4; ++r)
          ((u16*)dst)[base + (size_t)r * 64] = f2bf(fmaxf(acc[mf][nf][r] + bv, 0.f));
      } else {
        size_t o = (((size_t)b * 64 + oc) * 256 + y) * 256 + bx0 + kq * 4;
        f32x4 rx = *(const f32x4*)(resid + o);
        f32x4 vv;
#pragma unroll
        for (int r = 0; r < 4; ++r) vv[r] = rx[r] + acc[mf][nf][r] + bv;
        *(f32x4*)((float*)dst + o) = vv;
      }
    }
  }
}

extern "C" void kernel_launch(void* const* d_in, const int* in_sizes, int n_in,
                              void* d_out, int out_size, void* d_ws, size_t ws_size,
                              hipStream_t stream) {
  const float* x        = (const float*)d_in[0];
  const float* ow1      = (const float*)d_in[1];
  const float* ow2      = (const float*)d_in[2];
  const float* cw1      = (const float*)d_in[3];
  const float* cb1      = (const float*)d_in[4];
  const float* cw2      = (const float*)d_in[5];
  const float* cb2      = (const float*)d_in[6];
  const float* cw3      = (const float*)d_in[7];
  const float* cb3      = (const float*)d_in[8];
  const float* scale_w  = (const float*)d_in[9];
  const float* scale_b  = (const float*)d_in[10];
  const float* shift_w  = (const float*)d_in[11];
  const float* shift_b  = (const float*)d_in[12];
  const float* dyn1     = (const float*)d_in[13];
  const float* share1   = (const float*)d_in[14];
  const float* share1_b = (const float*)d_in[15];
  const float* dyn2     = (const float*)d_in[16];
  const float* share2   = (const float*)d_in[17];
  const float* share2_b = (const float*)d_in[18];
  float* out = (float*)d_out;

  char* p = (char*)d_ws;
  u16* xh   = (u16*)p;            p += (size_t)8 * 256 * 256 * 64 * 2;   // 67,108,864
  u16* midh = (u16*)p;            p += (size_t)8 * 256 * 256 * 64 * 2;   // 67,108,864
  u16* wbf1 = (u16*)p;            p += (size_t)8 * 64 * 576 * 2;         // 589,824
  u16* wbf2 = (u16*)p;            p += (size_t)8 * 64 * 576 * 2;
  u16* cwb1 = (u16*)p;            p += (size_t)32 * 3136 * 2;            // 200,704
  u16* cwb2 = (u16*)p;            p += (size_t)32 * 288 * 2;
  u16* cwb3 = (u16*)p;            p += (size_t)32 * 288 * 2;
  float* a_    = (float*)p;       p += 512 * 4;
  float* bias1 = (float*)p;       p += 512 * 4;
  float* bias2 = (float*)p;       p += 512 * 4;
  float* cond  = (float*)p;       p += 256 * 4;
  // cond-net temporaries overlap midh (dead before hda1 writes midh)
  u16* h1h = midh;                                   // 8*126*126*32 bf16
  u16* h2h = h1h + (size_t)8 * 126 * 126 * 32;       // 8*63*63*32 bf16
  float* h3 = (float*)(h2h + (size_t)8 * 63 * 63 * 32);  // 8*32*32*32 f32

  k_tr<<<dim3(8, 256, 8), 256, 0, stream>>>(x, xh);

  k_prep_cw<<<(32 * 3136 + 255) / 256, 256, 0, stream>>>(cw1, cwb1, 64, 49, 32 * 3136);
  k_prep_cw<<<(32 * 288 + 255) / 256, 256, 0, stream>>>(cw2, cwb2, 32, 9, 32 * 288);
  k_prep_cw<<<(32 * 288 + 255) / 256, 256, 0, stream>>>(cw3, cwb3, 32, 9, 32 * 288);

  k_conv_s2<256, 126, 64, 7, 0><<<dim3(8, 16, 8), 256, 0, stream>>>(xh, cwb1, cb1, h1h);
  k_conv_s2<126, 63, 32, 3, 0><<<dim3(4, 8, 8), 256, 0, stream>>>(h1h, cwb2, cb2, h2h);
  k_conv_s2<63, 32, 32, 3, 1><<<dim3(2, 4, 8), 256, 0, stream>>>(h2h, cwb3, cb3, h3);

  k_mean<<<256, 256, 0, stream>>>(h3, cond);
  k_film<<<1, 512, 0, stream>>>(cond, scale_w, scale_b, shift_w, shift_b,
                                share1_b, share2_b, a_, bias1, bias2);

  k_prep_hda<<<(8 * 64 * 576 + 255) / 256, 256, 0, stream>>>(dyn1, ow1, share1, a_, wbf1, 1);
  k_prep_hda<<<(8 * 64 * 576 + 255) / 256, 256, 0, stream>>>(dyn2, ow2, share2, a_, wbf2, 0);

  k_hda_mfma<1><<<dim3(16, 16, 8), 256, 0, stream>>>(xh, wbf1, bias1, nullptr, midh);
  k_hda_mfma<2><<<dim3(16, 16, 8), 256, 0, stream>>>(midh, wbf2, bias2, x, out);
}

// Round 3
// 413.746 us; speedup vs baseline: 5.4675x; 1.2035x over previous
//
#include <hip/hip_runtime.h>

typedef unsigned short u16;
typedef unsigned int u32;
typedef __attribute__((ext_vector_type(8))) __bf16 bf16x8;
typedef __attribute__((ext_vector_type(8))) u16 u16x8;
typedef __attribute__((ext_vector_type(4))) float f32x4;

__device__ __forceinline__ u16 f2bf(float f) {
  u32 u = __builtin_bit_cast(u32, f);
  u = (u + 0x7FFFu + ((u >> 16) & 1u)) >> 16;
  return (u16)u;
}

__device__ __forceinline__ f32x4 mfma16(bf16x8 a, bf16x8 b, f32x4 c) {
  return __builtin_amdgcn_mfma_f32_16x16x32_bf16(a, b, c, 0, 0, 0);
}

// ---------- NCHW f32 -> NHWC bf16 transpose of x ----------
__global__ __launch_bounds__(256) void k_tr(const float* __restrict__ x,
                                            u16* __restrict__ xh) {
  __shared__ float t[64][33];
  const int b = blockIdx.z, y = blockIdx.y, x0 = blockIdx.x * 32;
  const int tid = threadIdx.x;
  {
    int ic = tid >> 2, xo = (tid & 3) * 8;
    const float* s = x + (((size_t)b * 64 + ic) * 256 + y) * 256 + x0 + xo;
    f32x4 v0 = *(const f32x4*)s;
    f32x4 v1 = *(const f32x4*)(s + 4);
#pragma unroll
    for (int j = 0; j < 4; ++j) { t[ic][xo + j] = v0[j]; t[ic][xo + 4 + j] = v1[j]; }
  }
  __syncthreads();
  {
    int xc = tid >> 3, ic0 = (tid & 7) * 8;
    u16x8 v;
#pragma unroll
    for (int j = 0; j < 8; ++j) v[j] = f2bf(t[ic0 + j][xc]);
    *(u16x8*)(xh + (((size_t)b * 256 + y) * 256 + x0 + xc) * 64 + ic0) = v;
  }
}

// ---------- cond conv2/3 weights: [OC][IC][3][3] f32 -> [oc][tap*IC+ic] bf16 ----------
__global__ void k_prep_cw(const float* __restrict__ src, u16* __restrict__ dst,
                          int IC, int KK2, int n) {
  int d = blockIdx.x * 256 + threadIdx.x;
  if (d >= n) return;
  int per = KK2 * IC;
  int oc = d / per, r = d - oc * per;
  int tap = r / IC, ic = r - tap * IC;
  dst[d] = f2bf(src[(oc * IC + ic) * KK2 + tap]);
}

// ---------- conv1 weights: [32][64][7][7] f32 -> [oc][tap(50, zero-pad)][ic(64)] bf16 ----------
__global__ void k_prep_cw1(const float* __restrict__ src, u16* __restrict__ dst) {
  int d = blockIdx.x * 256 + threadIdx.x;  // 32*3200
  if (d >= 32 * 3200) return;
  int oc = d / 3200, r = d - oc * 3200;
  int tap = r >> 6, ic = r & 63;
  float v = (tap < 49) ? src[(oc * 64 + ic) * 49 + tap] : 0.f;
  dst[d] = f2bf(v);
}

// ---------- HDA weights: merge dyn*ow | share (optionally *a) -> [b][oc][576] bf16 ----------
__global__ void k_prep_hda(const float* __restrict__ dyn, const float* __restrict__ ow,
                           const float* __restrict__ share, const float* __restrict__ a_,
                           u16* __restrict__ dst, int use_a) {
  int d = blockIdx.x * 256 + threadIdx.x;
  if (d >= 8 * 64 * 576) return;
  int b = d / 36864, r = d - b * 36864;
  int oc = r / 576, k = r - oc * 576;
  int tap = k >> 6, ic = k & 63;
  float v = (oc < 32) ? dyn[(oc * 64 + ic) * 9 + tap] * ow[((b * 32 + oc) * 64 + ic) * 9 + tap]
                      : share[((oc - 32) * 64 + ic) * 9 + tap];
  if (use_a) v *= a_[b * 64 + oc];
  dst[d] = f2bf(v);
}

// ---------- cond conv1: 7x7 s2 p1 64->32, MFMA, LDS-staged ----------
// in: xh NHWC64 bf16; out: NHWC32 bf16 [8][126][126][32], relu
__global__ __launch_bounds__(256, 2) void k_cond1_mfma(const u16* __restrict__ xh,
    const u16* __restrict__ wgt /*[32][3200]*/, const float* __restrict__ cb,
    u16* __restrict__ dst) {
  __shared__ char lds[45120];  // 38x37 pos x 16 ic bf16, swizzled
  const int b = blockIdx.z;
  const int oh0 = blockIdx.y * 16, ow0 = blockIdx.x * 16;
  const int tid = threadIdx.x, lane = tid & 63, wid = tid >> 6;
  const int col = lane & 15, kq = lane >> 4;
  const int ihs = 2 * oh0 - 1, iws = 2 * ow0 - 1;
  const u16x8 Z = (u16x8)0;
  f32x4 acc[4][2];
#pragma unroll
  for (int i = 0; i < 4; ++i)
#pragma unroll
    for (int j = 0; j < 2; ++j) acc[i][j] = 0.f;
#pragma unroll 1
  for (int c = 0; c < 4; ++c) {  // 16-ic chunks
    __syncthreads();
    for (int i = tid; i < 2812; i += 256) {  // 38*37 pos x 2 halves
      int pos = i >> 1, half = i & 1;
      int r = pos / 37, cc = pos - r * 37;
      int gy = ihs + r, gx = iws + cc;
      u16x8 v = Z;
      if ((unsigned)gy < 256u && (unsigned)gx < 256u)
        v = *(const u16x8*)(xh + (((size_t)b * 256 + gy) * 256 + gx) * 64 + c * 16 + half * 8);
      int off = (pos * 32 + half * 16) ^ (((pos >> 1) & 7) << 4);
      *(u16x8*)(lds + off) = v;
    }
    __syncthreads();
#pragma unroll
    for (int s = 0; s < 25; ++s) {  // K-step: taps 2s (kq<2) | 2s+1 (kq>=2)
      const int t0 = 2 * s, t1 = 2 * s + 1;
      const int kh0 = t0 / 7, kw0 = t0 % 7;
      const int kh1 = t1 / 7, kw1 = t1 % 7;
      int hi = kq >> 1;
      int kh = hi ? kh1 : kh0;
      int kw = hi ? kw1 : kw0;
      int tap = hi ? t1 : t0;
      int hoff = (kq & 1) * 16;
      bf16x8 a[4];
#pragma unroll
      for (int mf = 0; mf < 4; ++mf) {
        int py = wid * 4 + mf;
        int pos = (2 * py + kh) * 37 + 2 * col + kw;
        int off = (pos * 32 + hoff) ^ (((pos >> 1) & 7) << 4);
        a[mf] = __builtin_bit_cast(bf16x8, *(const u16x8*)(lds + off));
      }
      bf16x8 w[2];
#pragma unroll
      for (int nf = 0; nf < 2; ++nf)
        w[nf] = __builtin_bit_cast(bf16x8,
            *(const u16x8*)(wgt + (nf * 16 + col) * 3200 + tap * 64 + c * 16 + (kq & 1) * 8));
#pragma unroll
      for (int mf = 0; mf < 4; ++mf)
#pragma unroll
        for (int nf = 0; nf < 2; ++nf) acc[mf][nf] = mfma16(a[mf], w[nf], acc[mf][nf]);
    }
  }
  const int px0 = ow0 + kq * 4;
#pragma unroll
  for (int mf = 0; mf < 4; ++mf) {
    int oh = oh0 + wid * 4 + mf;
    if (oh >= 126) continue;
#pragma unroll
    for (int nf = 0; nf < 2; ++nf) {
      int oc = nf * 16 + col;
      float bv = cb[oc];
#pragma unroll
      for (int r = 0; r < 4; ++r) {
        int ow = px0 + r;
        if (ow < 126)
          dst[(((size_t)b * 126 + oh) * 126 + ow) * 32 + oc] =
              f2bf(fmaxf(acc[mf][nf][r] + bv, 0.f));
      }
    }
  }
}

// ---------- generic stride-2 pad-1 conv, 32 oc, MFMA, A from global NHWC bf16 ----------
// (now used only for the small conv2/conv3)
template <int HI, int HO, int IC, int KK, int OUTF32>
__global__ __launch_bounds__(256, 4) void k_conv_s2(const u16* __restrict__ src,
    const u16* __restrict__ wgt, const float* __restrict__ bias, void* __restrict__ dst) {
  const int b = blockIdx.z;
  const int by0 = blockIdx.y * 8, bx0 = blockIdx.x * 16;
  const int tid = threadIdx.x, lane = tid & 63, wid = tid >> 6;
  const int col = lane & 15, kq = lane >> 4;
  f32x4 acc[2][2];
#pragma unroll
  for (int i = 0; i < 2; ++i)
#pragma unroll
    for (int j = 0; j < 2; ++j) acc[i][j] = 0.f;
  const u16x8 Z = (u16x8)0;
#pragma unroll
  for (int kh = 0; kh < KK; ++kh) {
#pragma unroll
    for (int kw = 0; kw < KK; ++kw) {
#pragma unroll
      for (int h = 0; h < IC / 32; ++h) {
        bf16x8 a[2];
#pragma unroll
        for (int mf = 0; mf < 2; ++mf) {
          int oh = by0 + wid * 2 + mf;
          int ih = 2 * oh - 1 + kh;
          int ix = 2 * (bx0 + col) - 1 + kw;
          int ic = h * 32 + kq * 8;
          u16x8 raw = Z;
          if ((unsigned)ih < (unsigned)HI && (unsigned)ix < (unsigned)HI)
            raw = *(const u16x8*)(src + (((size_t)b * HI + ih) * HI + ix) * IC + ic);
          a[mf] = __builtin_bit_cast(bf16x8, raw);
        }
        int k0 = (kh * KK + kw) * IC + h * 32 + kq * 8;
        bf16x8 w[2];
#pragma unroll
        for (int nf = 0; nf < 2; ++nf)
          w[nf] = __builtin_bit_cast(bf16x8,
                    *(const u16x8*)(wgt + (size_t)(nf * 16 + col) * (KK * KK * IC) + k0));
#pragma unroll
        for (int mf = 0; mf < 2; ++mf)
#pragma unroll
          for (int nf = 0; nf < 2; ++nf) acc[mf][nf] = mfma16(a[mf], w[nf], acc[mf][nf]);
      }
    }
  }
#pragma unroll
  for (int mf = 0; mf < 2; ++mf) {
    int oh = by0 + wid * 2 + mf;
    if (oh >= HO) continue;
#pragma unroll
    for (int nf = 0; nf < 2; ++nf) {
      int oc = nf * 16 + col;
      float bv = bias[oc];
#pragma unroll
      for (int r = 0; r < 4; ++r) {
        int ow = bx0 + kq * 4 + r;
        if (ow >= HO) continue;
        float v = fmaxf(acc[mf][nf][r] + bv, 0.f);
        if (OUTF32)
          ((float*)dst)[(((size_t)b * 32 + oc) * HO + oh) * HO + ow] = v;
        else
          ((u16*)dst)[(((size_t)b * HO + oh) * HO + ow) * 32 + oc] = f2bf(v);
      }
    }
  }
}

// ---------- mean over 32x32 -> cond[8*32] ----------
__global__ void k_mean(const float* __restrict__ h3, float* __restrict__ cond) {
  int bo = blockIdx.x;
  int tid = threadIdx.x;
  float s = 0.f;
  for (int i = tid; i < 1024; i += 256) s += h3[bo * 1024 + i];
  __shared__ float red[256];
  red[tid] = s;
  __syncthreads();
  for (int o = 128; o > 0; o >>= 1) {
    if (tid < o) red[tid] += red[tid + o];
    __syncthreads();
  }
  if (tid == 0) cond[bo] = red[0] * (1.f / 1024.f);
}

// ---------- FiLM fold ----------
__global__ void k_film(const float* __restrict__ cond,
                       const float* __restrict__ scale_w, const float* __restrict__ scale_b,
                       const float* __restrict__ shift_w, const float* __restrict__ shift_b,
                       const float* __restrict__ share1_b, const float* __restrict__ share2_b,
                       float* __restrict__ a_, float* __restrict__ bias1,
                       float* __restrict__ bias2) {
  int t = threadIdx.x;  // 512
  int b = t >> 6, j = t & 63;
  float s = scale_b[j], sh = shift_b[j];
  for (int k = 0; k < 32; ++k) {
    float c = cond[b * 32 + k];
    s = fmaf(c, scale_w[j * 32 + k], s);
    sh = fmaf(c, shift_w[j * 32 + k], sh);
  }
  float a = s + 1.f;
  float b0 = (j < 32) ? 0.f : share1_b[j - 32];
  a_[t] = a;
  bias1[t] = fmaf(a, b0, sh);
  bias2[t] = (j < 32) ? 0.f : share2_b[j - 32];
}

// ---------- HDA conv 3x3 s1 p1 64->64, MFMA, LDS-staged 16x16 tile ----------
template <int STAGE>
__global__ __launch_bounds__(256, 3) void k_hda_mfma(const u16* __restrict__ asrc,
    const u16* __restrict__ wall, const float* __restrict__ bias,
    const float* __restrict__ resid, void* __restrict__ dst) {
  __shared__ char lds[41472];  // 18*18 positions x 64 ic bf16, swizzled
  const int b = blockIdx.z;
  const int by0 = blockIdx.y * 16, bx0 = blockIdx.x * 16;
  const int tid = threadIdx.x;
  const u16x8 Z = (u16x8)0;
  for (int i = tid; i < 2592; i += 256) {
    int L = i >> 3, c = i & 7;
    int yy = L / 18, xx = L - yy * 18;
    int gy = by0 - 1 + yy, gx = bx0 - 1 + xx;
    u16x8 v = Z;
    if ((unsigned)gy < 256u && (unsigned)gx < 256u)
      v = *(const u16x8*)(asrc + (((size_t)b * 256 + gy) * 256 + gx) * 64 + c * 8);
    int off = (L * 128 + c * 16) ^ ((L & 7) << 4);
    *(u16x8*)(lds + off) = v;
  }
  __syncthreads();
  const int lane = tid & 63, wid = tid >> 6;
  const int col = lane & 15, kq = lane >> 4;
  f32x4 acc[4][4];
#pragma unroll
  for (int i = 0; i < 4; ++i)
#pragma unroll
    for (int j = 0; j < 4; ++j) acc[i][j] = 0.f;
  const u16* wb = wall + (size_t)b * 64 * 576;
#pragma unroll 3
  for (int tap = 0; tap < 9; ++tap) {
    const int kh = tap / 3, kw = tap - kh * 3;
#pragma unroll
    for (int h = 0; h < 2; ++h) {
      bf16x8 a[4];
#pragma unroll
      for (int mf = 0; mf < 4; ++mf) {
        int L = (wid * 4 + mf + kh) * 18 + (col + kw);
        int ic = h * 32 + kq * 8;
        int off = (L * 128 + ic * 2) ^ ((L & 7) << 4);
        a[mf] = __builtin_bit_cast(bf16x8, *(const u16x8*)(lds + off));
      }
      int k0 = tap * 64 + h * 32 + kq * 8;
      bf16x8 w[4];
#pragma unroll
      for (int nf = 0; nf < 4; ++nf)
        w[nf] = __builtin_bit_cast(bf16x8, *(const u16x8*)(wb + (size_t)(nf * 16 + col) * 576 + k0));
#pragma unroll
      for (int mf = 0; mf < 4; ++mf)
#pragma unroll
        for (int nf = 0; nf < 4; ++nf) acc[mf][nf] = mfma16(a[mf], w[nf], acc[mf][nf]);
    }
  }
  const float* bb = bias + b * 64;
#pragma unroll
  for (int mf = 0; mf < 4; ++mf) {
    int y = by0 + wid * 4 + mf;
#pragma unroll
    for (int nf = 0; nf < 4; ++nf) {
      int oc = nf * 16 + col;
      float bv = bb[oc];
      if (STAGE == 1) {
        size_t base = (((size_t)b * 256 + y) * 256 + (bx0 + kq * 4)) * 64 + oc;
#pragma unroll
        for (int r = 0; r < 4; ++r)
          ((u16*)dst)[base + (size_t)r * 64] = f2bf(fmaxf(acc[mf][nf][r] + bv, 0.f));
      } else {
        size_t o = (((size_t)b * 64 + oc) * 256 + y) * 256 + bx0 + kq * 4;
        f32x4 rx = *(const f32x4*)(resid + o);
        f32x4 vv;
#pragma unroll
        for (int r = 0; r < 4; ++r) vv[r] = rx[r] + acc[mf][nf][r] + bv;
        *(f32x4*)((float*)dst + o) = vv;
      }
    }
  }
}

extern "C" void kernel_launch(void* const* d_in, const int* in_sizes, int n_in,
                              void* d_out, int out_size, void* d_ws, size_t ws_size,
                              hipStream_t stream) {
  const float* x        = (const float*)d_in[0];
  const float* ow1      = (const float*)d_in[1];
  const float* ow2      = (const float*)d_in[2];
  const float* cw1      = (const float*)d_in[3];
  const float* cb1      = (const float*)d_in[4];
  const float* cw2      = (const float*)d_in[5];
  const float* cb2      = (const float*)d_in[6];
  const float* cw3      = (const float*)d_in[7];
  const float* cb3      = (const float*)d_in[8];
  const float* scale_w  = (const float*)d_in[9];
  const float* scale_b  = (const float*)d_in[10];
  const float* shift_w  = (const float*)d_in[11];
  const float* shift_b  = (const float*)d_in[12];
  const float* dyn1     = (const float*)d_in[13];
  const float* share1   = (const float*)d_in[14];
  const float* share1_b = (const float*)d_in[15];
  const float* dyn2     = (const float*)d_in[16];
  const float* share2   = (const float*)d_in[17];
  const float* share2_b = (const float*)d_in[18];
  float* out = (float*)d_out;

  char* p = (char*)d_ws;
  u16* xh   = (u16*)p;            p += (size_t)8 * 256 * 256 * 64 * 2;
  u16* midh = (u16*)p;            p += (size_t)8 * 256 * 256 * 64 * 2;
  u16* wbf1 = (u16*)p;            p += (size_t)8 * 64 * 576 * 2;
  u16* wbf2 = (u16*)p;            p += (size_t)8 * 64 * 576 * 2;
  u16* cwb1 = (u16*)p;            p += (size_t)32 * 3200 * 2;
  u16* cwb2 = (u16*)p;            p += (size_t)32 * 288 * 2;
  u16* cwb3 = (u16*)p;            p += (size_t)32 * 288 * 2;
  float* a_    = (float*)p;       p += 512 * 4;
  float* bias1 = (float*)p;       p += 512 * 4;
  float* bias2 = (float*)p;       p += 512 * 4;
  float* cond  = (float*)p;       p += 256 * 4;
  // cond-net temporaries overlap midh (dead before hda1 writes midh)
  u16* h1h = midh;                                   // 8*126*126*32 bf16
  u16* h2h = h1h + (size_t)8 * 126 * 126 * 32;       // 8*63*63*32 bf16
  float* h3 = (float*)(h2h + (size_t)8 * 63 * 63 * 32);  // 8*32*32*32 f32

  k_tr<<<dim3(8, 256, 8), 256, 0, stream>>>(x, xh);

  k_prep_cw1<<<(32 * 3200 + 255) / 256, 256, 0, stream>>>(cw1, cwb1);
  k_prep_cw<<<(32 * 288 + 255) / 256, 256, 0, stream>>>(cw2, cwb2, 32, 9, 32 * 288);
  k_prep_cw<<<(32 * 288 + 255) / 256, 256, 0, stream>>>(cw3, cwb3, 32, 9, 32 * 288);

  k_cond1_mfma<<<dim3(8, 8, 8), 256, 0, stream>>>(xh, cwb1, cb1, h1h);
  k_conv_s2<126, 63, 32, 3, 0><<<dim3(4, 8, 8), 256, 0, stream>>>(h1h, cwb2, cb2, h2h);
  k_conv_s2<63, 32, 32, 3, 1><<<dim3(2, 4, 8), 256, 0, stream>>>(h2h, cwb3, cb3, h3);

  k_mean<<<256, 256, 0, stream>>>(h3, cond);
  k_film<<<1, 512, 0, stream>>>(cond, scale_w, scale_b, shift_w, shift_b,
                                share1_b, share2_b, a_, bias1, bias2);

  k_prep_hda<<<(8 * 64 * 576 + 255) / 256, 256, 0, stream>>>(dyn1, ow1, share1, a_, wbf1, 1);
  k_prep_hda<<<(8 * 64 * 576 + 255) / 256, 256, 0, stream>>>(dyn2, ow2, share2, a_, wbf2, 0);

  k_hda_mfma<1><<<dim3(16, 16, 8), 256, 0, stream>>>(xh, wbf1, bias1, nullptr, midh);
  k_hda_mfma<2><<<dim3(16, 16, 8), 256, 0, stream>>>(midh, wbf2, bias2, x, out);
}